// Round 1
// baseline (99.373 us; speedup 1.0000x reference)
//
#include <hip/hip_runtime.h>
#include <math.h>

#define T 8192
#define D 36
#define NCH 16
#define CHUNK (T / NCH)    // 512
#define RPT (CHUNK / 256)  // 2 K-rows per thread when staging

// ws layout (floats):
// [0, 2T*NCH)            pv  (chunk-major: pv[c*2T + prow])
// [2T*NCH, 4T*NCH)       pi  (int, same layout)

__device__ __forceinline__ void load_row(const float* __restrict__ E, int j,
                                         float* e) {
    // row byte offset = j*144, 16B aligned -> 9 float4 loads
    const float4* Er = (const float4*)(E + j * D);
#pragma unroll
    for (int i = 0; i < D / 4; ++i) {
        float4 v = Er[i];
        e[4 * i + 0] = v.x;
        e[4 * i + 1] = v.y;
        e[4 * i + 2] = v.z;
        e[4 * i + 3] = v.w;
    }
}

// grid: (T/256 row-blocks, NCH chunks, 2 heads), block 256
// Each block: computes its K-chunk from E into LDS (redundant across row-blocks,
// but only ~290 fma/thread vs ~3K fma/thread of scan), computes own-row Q in
// registers, then scans the chunk. No Q/K ever touches global memory.
__global__ __launch_bounds__(256) void fused_proj_argmax(
    const float* __restrict__ E,
    const float* __restrict__ WQp, const float* __restrict__ WKp,
    const float* __restrict__ WQs, const float* __restrict__ WKs,
    float* __restrict__ pv, int* __restrict__ pi) {
    const int head = blockIdx.z;
    const float* __restrict__ WQ = head ? WQs : WQp;
    const float* __restrict__ WK = head ? WKs : WKp;

    __shared__ float2 sk[CHUNK];
    const int j0 = blockIdx.y * CHUNK;

    // --- stage K chunk into LDS (same fmaf chain order as original proj:
    // d ascending => bit-identical K values) ---
#pragma unroll
    for (int r = 0; r < RPT; ++r) {
        const int j = j0 + r * 256 + threadIdx.x;
        float e[D];
        load_row(E, j, e);
        float k0 = 0.f, k1 = 0.f;
#pragma unroll
        for (int d = 0; d < D; ++d) {
            k0 = fmaf(e[d], WK[d], k0);
            k1 = fmaf(e[d], WK[D + d], k1);
        }
        sk[r * 256 + threadIdx.x] = make_float2(k0, k1);
    }

    // --- own-row Q in registers (bit-identical chain) ---
    const int row = blockIdx.x * 256 + threadIdx.x;
    float q0 = 0.f, q1 = 0.f;
    {
        float e[D];
        load_row(E, row, e);
#pragma unroll
        for (int d = 0; d < D; ++d) {
            q0 = fmaf(e[d], WQ[d], q0);
            q1 = fmaf(e[d], WQ[D + d], q1);
        }
    }
    __syncthreads();

    // --- scan: identical score expression as before ---
    float best = -INFINITY;
    int bi = 0;
#pragma unroll 8
    for (int k = 0; k < CHUNK; ++k) {
        float2 kk = sk[k];
        float s = fmaf(q0, kk.x, q1 * kk.y);
        bool gt = s > best;  // strict > keeps first occurrence within chunk
        best = gt ? s : best;
        bi = gt ? k : bi;
    }
    const int prow = head * T + row;
    pv[blockIdx.y * 2 * T + prow] = best;   // coalesced write
    pi[blockIdx.y * 2 * T + prow] = j0 + bi;
}

// Cross-chunk reduce + compute V[best] directly from E[best] (same fmaf
// chain order as the original proj's V accumulators => bit-identical).
__global__ __launch_bounds__(256) void finalize_fused(
    const float* __restrict__ E,
    const float* __restrict__ WVop, const float* __restrict__ WVarg,
    const float* __restrict__ WVs,
    const float* __restrict__ pv, const int* __restrict__ pi,
    float* __restrict__ out) {
    const int idx = blockIdx.x * blockDim.x + threadIdx.x;  // 0 .. 2T-1
    if (idx >= 2 * T) return;
    const int head = idx >> 13;  // idx / T  (uniform per block)
    const int row = idx & (T - 1);

    float best = -INFINITY;
    int bi = 0;
#pragma unroll
    for (int c = 0; c < NCH; ++c) {  // ascending chunk => first occurrence
        float v = pv[c * 2 * T + idx];  // coalesced
        int i2 = pi[c * 2 * T + idx];
        bool gt = v > best;
        best = gt ? v : best;
        bi = gt ? i2 : bi;
    }

    float e[D];
    load_row(E, bi, e);  // 144B gather, E is L2-resident
    if (head == 0) {
        float vop = 0.f, varg = 0.f;
#pragma unroll
        for (int d = 0; d < D; ++d) {
            vop = fmaf(e[d], WVop[d], vop);
            varg = fmaf(e[d], WVarg[d], varg);
        }
        out[row] = vop;
        out[T + row] = varg;
    } else {
        float vs = 0.f;
#pragma unroll
        for (int d = 0; d < D; ++d) vs = fmaf(e[d], WVs[d], vs);
        out[2 * T + row] = vs;
    }
}

extern "C" void kernel_launch(void* const* d_in, const int* in_sizes, int n_in,
                              void* d_out, int out_size, void* d_ws,
                              size_t ws_size, hipStream_t stream) {
    const float* E = (const float*)d_in[0];
    const float* WQp = (const float*)d_in[1];
    const float* WKp = (const float*)d_in[2];
    const float* WVop = (const float*)d_in[3];
    const float* WVarg = (const float*)d_in[4];
    const float* WQs = (const float*)d_in[5];
    const float* WKs = (const float*)d_in[6];
    const float* WVs = (const float*)d_in[7];
    float* out = (float*)d_out;

    float* pv = (float*)d_ws;
    int* pi = (int*)((float*)d_ws + 2 * T * NCH);

    dim3 gA(T / 256, NCH, 2);
    fused_proj_argmax<<<gA, 256, 0, stream>>>(E, WQp, WKp, WQs, WKs, pv, pi);

    finalize_fused<<<(2 * T) / 256, 256, 0, stream>>>(E, WVop, WVarg, WVs, pv,
                                                      pi, out);
}